// Round 13
// baseline (298.876 us; speedup 1.0000x reference)
//
#include <hip/hip_runtime.h>

#define N_NODES 50000
#define N_EDGES 800000
#define NBINS 64
#define BIN_NODES 784            // 64*784 = 50176 >= 50000
#define EPB 1024                 // edges per block in hist/scatter (256 thr x 4)
#define NBLK_E ((N_EDGES + EPB - 1) / EPB)   // 782
// D_S=64, D_R=16, D_E=64, D_X=16, D_P=64, NUM_CLASSES=10
//
// scores[n] = u0[n] + deg_n*u1[n] + sum_{e->n} w_e ,  w_e = u_s[s_e] + R_a[e]@A_R
//   u_s = O@A_S ; u0 = O@A_O + X@A_X + c1 ; u1 = O@A_dO + c0
// (folded tables as in prior rounds; A layout [226][16], cols 10..15 zero)
//
// r12 lesson: exact-CSR scatter of 20 B records = random stores -> L3 RMW
// store-queue wall (~50 us, VALU 5%, ILP-invariant). This round: 64-bin
// counting sort. Scatter writes are block-claimed contiguous per-bin runs
// (full lines, no RMW); reduction accumulates scores+degree in LDS and
// fuses the softmax epilogue. count_rank/alloc/node_score deleted.

// ---------------------------------------------------------------------------
// Workspace layout (bytes) — end = 25,665,536 < 26,414,400 (proven r3)
// ---------------------------------------------------------------------------
#define WS_A       ((size_t)0)         // 14,464 B
#define WS_BCOUNT  ((size_t)16384)     // 64 counters, stride 16 dwords (4 KB)
#define WS_BBASE   ((size_t)20480)     // 65 i32
#define WS_BCUR    ((size_t)20992)     // 64 counters, stride 16 dwords (4 KB)
#define WS_US      ((size_t)65536)     // 50000*12 f32 = 2,400,000
#define WS_U01     ((size_t)2465536)   // 50000*20 f32 = 4,000,000
#define WS_PAY     ((size_t)6465536)   // 800000 * 24 B = 19,200,000

__device__ __forceinline__ unsigned int f32_to_bf16_rne(float f) {
    unsigned int x = __float_as_uint(f);
    return (x + 0x7fffu + ((x >> 16) & 1u)) >> 16;
}

// ---------------------------------------------------------------------------
// Precompute folded weight table A — 10 blocks, redundant Wc2 in LDS
// ---------------------------------------------------------------------------
__global__ __launch_bounds__(256) void precompute_A(
    const float* __restrict__ W_r, const float* __restrict__ b_r,
    const float* __restrict__ W_o, const float* __restrict__ b_o,
    const float* __restrict__ W_s, const float* __restrict__ b_s,
    float* __restrict__ A)
{
    __shared__ float Wc2[640];  // Wc rows 80..143 (64 x 10)
    const int t = threadIdx.x;

    for (int idx = t; idx < 640; idx += 256) {
        const int row = 80 + idx / 10, c = idx % 10;
        float acc = 0.f;
        for (int j = 0; j < 64; ++j)
            acc = fmaf(W_o[row * 64 + j], W_s[j * 10 + c], acc);
        Wc2[idx] = acc;
    }
    __syncthreads();

    for (int g = blockIdx.x * 256 + t; g < 3616; g += gridDim.x * 256) {
        if (g < 1356) {
            const int row = g / 6, c = 10 + g % 6;
            A[row * 16 + c] = 0.f;
        } else if (g < 2156) {
            const int i = g - 1356, row = i / 10, c = i % 10;
            float acc = 0.f;
            for (int j = 0; j < 64; ++j)
                acc = fmaf(W_o[row * 64 + j], W_s[j * 10 + c], acc);
            A[row * 16 + c] = acc;
        } else if (g < 3596) {
            const int i = g - 2156, k = i / 10, c = i % 10;
            const int wrow = (k < 64) ? k : (k < 80 ? 128 + (k - 64) : 64 + (k - 80));
            const int arow = (k < 64) ? 80 + k : (k < 80 ? 144 + (k - 64) : 160 + (k - 80));
            const float* src = W_r + (size_t)wrow * 64;
            float acc = 0.f;
            for (int m = 0; m < 64; ++m)
                acc = fmaf(src[m], Wc2[m * 10 + c], acc);
            A[arow * 16 + c] = acc;
        } else if (g < 3606) {
            const int c = g - 3596;
            float acc = 0.f;
            for (int m = 0; m < 64; ++m)
                acc = fmaf(b_r[m], Wc2[m * 10 + c], acc);
            A[224 * 16 + c] = acc;
        } else {
            const int c = g - 3606;
            float acc = b_s[c];
            for (int j = 0; j < 64; ++j)
                acc = fmaf(b_o[j], W_s[j * 10 + c], acc);
            A[225 * 16 + c] = acc;
        }
    }
}

// ---------------------------------------------------------------------------
// Per-node 10-vectors (r11 structure, unchanged): thread = (node, class-PAIR)
// ---------------------------------------------------------------------------
__global__ __launch_bounds__(256) void node_u_kernel(
    const float* __restrict__ O, const float* __restrict__ X,
    const float* __restrict__ A,
    float* __restrict__ us, float* __restrict__ u01)
{
    __shared__ float2 lA[226 * 5];
    const int t = threadIdx.x;
    for (int i = t; i < 226 * 5; i += 256) {
        const int row = i / 5, cp = i - row * 5;
        lA[i] = *reinterpret_cast<const float2*>(A + (size_t)row * 16 + 2 * cp);
    }
    __syncthreads();

    const int tid = blockIdx.x * 256 + t;
    if (tid >= N_NODES * 5) return;
    const int n = tid / 5;
    const int cp = tid - n * 5;

    float vs0 = 0.f, vs1 = 0.f, v00 = 0.f, v01 = 0.f, v10 = 0.f, v11 = 0.f;

    const float4* Ov = reinterpret_cast<const float4*>(O + (size_t)n * 64);
#pragma unroll
    for (int kc = 0; kc < 16; ++kc) {
        const float4 o4 = Ov[kc];
#pragma unroll
        for (int j = 0; j < 4; ++j) {
            const float ov = (j == 0) ? o4.x : (j == 1) ? o4.y : (j == 2) ? o4.z : o4.w;
            const int k = kc * 4 + j;
            const float2 aO = lA[k * 5 + cp];
            const float2 aS = lA[(80 + k) * 5 + cp];
            const float2 aD = lA[(160 + k) * 5 + cp];
            v00 = fmaf(ov, aO.x, v00); v01 = fmaf(ov, aO.y, v01);
            vs0 = fmaf(ov, aS.x, vs0); vs1 = fmaf(ov, aS.y, vs1);
            v10 = fmaf(ov, aD.x, v10); v11 = fmaf(ov, aD.y, v11);
        }
    }
    const float4* Xv = reinterpret_cast<const float4*>(X + (size_t)n * 16);
#pragma unroll
    for (int kc = 0; kc < 4; ++kc) {
        const float4 x4 = Xv[kc];
#pragma unroll
        for (int j = 0; j < 4; ++j) {
            const float xv = (j == 0) ? x4.x : (j == 1) ? x4.y : (j == 2) ? x4.z : x4.w;
            const int k = 64 + kc * 4 + j;
            const float2 aX = lA[k * 5 + cp];
            v00 = fmaf(xv, aX.x, v00); v01 = fmaf(xv, aX.y, v01);
        }
    }

    const float2 c0 = lA[224 * 5 + cp];
    const float2 c1 = lA[225 * 5 + cp];
    *reinterpret_cast<float2*>(us + (size_t)n * 12 + 2 * cp) = make_float2(vs0, vs1);
    *reinterpret_cast<float2*>(u01 + (size_t)n * 20 + 2 * cp) =
        make_float2(v00 + c1.x, v01 + c1.y);
    *reinterpret_cast<float2*>(u01 + (size_t)n * 20 + 10 + 2 * cp) =
        make_float2(v10 + c0.x, v11 + c0.y);
}

// ---------------------------------------------------------------------------
// Global 64-bin histogram: LDS per-block hist, then <=64 line-padded atomics.
// ---------------------------------------------------------------------------
__global__ __launch_bounds__(256) void hist_kernel(
    const int* __restrict__ receivers, int* __restrict__ bcount)
{
    __shared__ int h[NBINS];
    const int t = threadIdx.x;
    if (t < NBINS) h[t] = 0;
    __syncthreads();
    const int t4 = blockIdx.x * 256 + t;
    if (t4 * 4 < N_EDGES) {
        const int4 r4 = reinterpret_cast<const int4*>(receivers)[t4];
        atomicAdd(&h[r4.x / BIN_NODES], 1);
        atomicAdd(&h[r4.y / BIN_NODES], 1);
        atomicAdd(&h[r4.z / BIN_NODES], 1);
        atomicAdd(&h[r4.w / BIN_NODES], 1);
    }
    __syncthreads();
    if (t < NBINS && h[t] > 0) atomicAdd(bcount + t * 16, h[t]);
}

// ---------------------------------------------------------------------------
// Tiny scan over 64 bins (1 wave): bases + cursors.
// ---------------------------------------------------------------------------
__global__ __launch_bounds__(64) void scan_kernel(
    const int* __restrict__ bcount, int* __restrict__ bbase, int* __restrict__ bcur)
{
    const int t = threadIdx.x;  // 0..63
    const int v = bcount[t * 16];
    int pre = v;
#pragma unroll
    for (int d = 1; d < 64; d <<= 1) {
        const int u = __shfl_up(pre, d);
        if (t >= d) pre += u;
    }
    const int ex = pre - v;
    bbase[t] = ex;
    bcur[t * 16] = ex;
    if (t == 63) bbase[64] = pre;
}

// ---------------------------------------------------------------------------
// Bin scatter: stream edges; compute w_e; block claims contiguous per-bin
// ranges (1 global atomic per bin per block); records written as
// near-sequential runs per bin -> full-line writes, no RMW wall.
// Record = 6 dwords: 5x bf16-pair + local node id.
// ---------------------------------------------------------------------------
__global__ __launch_bounds__(256) void bin_scatter_kernel(
    const float* __restrict__ R_a,
    const int* __restrict__ senders, const int* __restrict__ receivers,
    const float* __restrict__ us, const float* __restrict__ A,
    int* __restrict__ bcur,
    unsigned int* __restrict__ pay)
{
    __shared__ int h[NBINS];
    __shared__ int basep[NBINS];
    __shared__ int cur[NBINS];
    const int t = threadIdx.x;
    if (t < NBINS) h[t] = 0;
    __syncthreads();

    const int e0 = blockIdx.x * EPB + t * 4;
    const bool valid = (e0 < N_EDGES);   // N_EDGES % 4 == 0
    int4 r4 = make_int4(0, 0, 0, 0);
    int b0 = 0, b1 = 0, b2 = 0, b3 = 0;
    if (valid) {
        r4 = reinterpret_cast<const int4*>(receivers)[e0 >> 2];
        b0 = r4.x / BIN_NODES; b1 = r4.y / BIN_NODES;
        b2 = r4.z / BIN_NODES; b3 = r4.w / BIN_NODES;
        atomicAdd(&h[b0], 1); atomicAdd(&h[b1], 1);
        atomicAdd(&h[b2], 1); atomicAdd(&h[b3], 1);
    }
    __syncthreads();
    if (t < NBINS) {
        const int c = h[t];
        basep[t] = (c > 0) ? atomicAdd(bcur + t * 16, c) : 0;
        cur[t] = 0;
    }
    __syncthreads();
    if (!valid) return;

    const int4 s4 = reinterpret_cast<const int4*>(senders)[e0 >> 2];

#pragma unroll
    for (int j = 0; j < 4; ++j) {
        const int e = e0 + j;
        const int r = (j == 0) ? r4.x : (j == 1) ? r4.y : (j == 2) ? r4.z : r4.w;
        const int s = (j == 0) ? s4.x : (j == 1) ? s4.y : (j == 2) ? s4.z : s4.w;
        const int b = (j == 0) ? b0 : (j == 1) ? b1 : (j == 2) ? b2 : b3;
        const int nl = r - b * BIN_NODES;           // local node id in bin
        const int rk = atomicAdd(&cur[b], 1);       // LDS rank
        const int pos = basep[b] + rk;

        // w = u_s[s] + R_a[e] @ A_R
        const float4* U = reinterpret_cast<const float4*>(us + (size_t)s * 12);
        const float4 ua = U[0], ub = U[1], uc = U[2];
        float a[10] = {ua.x, ua.y, ua.z, ua.w, ub.x, ub.y, ub.z, ub.w, uc.x, uc.y};

        const float4* Rv = reinterpret_cast<const float4*>(R_a + (size_t)e * 16);
#pragma unroll
        for (int kc = 0; kc < 4; ++kc) {
            const float4 b4 = Rv[kc];
            const float* A0 = A + (size_t)(144 + kc * 4) * 16;
#pragma unroll
            for (int c = 0; c < 10; ++c) a[c] = fmaf(b4.x, A0[c], a[c]);
#pragma unroll
            for (int c = 0; c < 10; ++c) a[c] = fmaf(b4.y, A0[16 + c], a[c]);
#pragma unroll
            for (int c = 0; c < 10; ++c) a[c] = fmaf(b4.z, A0[32 + c], a[c]);
#pragma unroll
            for (int c = 0; c < 10; ++c) a[c] = fmaf(b4.w, A0[48 + c], a[c]);
        }

        unsigned int* wp = pay + (size_t)pos * 6;   // 24 B, 8-aligned
        uint2 q0, q1, q2;
        q0.x = f32_to_bf16_rne(a[0]) | (f32_to_bf16_rne(a[1]) << 16);
        q0.y = f32_to_bf16_rne(a[2]) | (f32_to_bf16_rne(a[3]) << 16);
        q1.x = f32_to_bf16_rne(a[4]) | (f32_to_bf16_rne(a[5]) << 16);
        q1.y = f32_to_bf16_rne(a[6]) | (f32_to_bf16_rne(a[7]) << 16);
        q2.x = f32_to_bf16_rne(a[8]) | (f32_to_bf16_rne(a[9]) << 16);
        q2.y = (unsigned int)nl;
        reinterpret_cast<uint2*>(wp)[0] = q0;
        reinterpret_cast<uint2*>(wp)[1] = q1;
        reinterpret_cast<uint2*>(wp)[2] = q2;
    }
}

// ---------------------------------------------------------------------------
// Bin reduce + fused head/softmax: one block per bin. Streams the bin's
// records contiguously, accumulates scores (f32) and degree in LDS, then
// computes probs for the bin's 784 nodes and writes out.
// ---------------------------------------------------------------------------
__global__ __launch_bounds__(1024) void bin_reduce_kernel(
    const unsigned int* __restrict__ pay,
    const int* __restrict__ bbase,
    const float* __restrict__ u01,
    float* __restrict__ out)
{
    __shared__ float acc[BIN_NODES * 10];  // 31,360 B
    __shared__ int   deg[BIN_NODES];       //  3,136 B
    const int b = blockIdx.x;
    const int t = threadIdx.x;

    for (int i = t; i < BIN_NODES * 10; i += 1024) acc[i] = 0.f;
    for (int i = t; i < BIN_NODES; i += 1024) deg[i] = 0;
    __syncthreads();

    const int lo = bbase[b];
    const int cnt = bbase[b + 1] - lo;
    const int gid = t >> 4, lane = t & 15;

    for (int i = gid; i < cnt; i += 64) {
        const unsigned int* rec = pay + (size_t)(lo + i) * 6;
        const unsigned int nl = rec[5];
        if (lane < 10) {
            const unsigned int dw = rec[lane >> 1];
            const float w = __uint_as_float((dw >> ((lane & 1) * 16)) << 16);
            atomicAdd(&acc[nl * 10 + lane], w);
        } else if (lane == 10) {
            atomicAdd(&deg[nl], 1);
        }
    }
    __syncthreads();

    // fused head + softmax epilogue: 16-lane group per node
    for (int nl = gid; nl < BIN_NODES; nl += 64) {
        const int n = b * BIN_NODES + nl;
        if (n < N_NODES) {
            const int cc = (lane < 10) ? lane : 0;
            const float dg = (float)deg[nl];
            float sc = u01[(size_t)n * 20 + cc]
                     + dg * u01[(size_t)n * 20 + 10 + cc]
                     + acc[nl * 10 + cc];
            float m = (lane < 10) ? sc : -3.0e38f;
#pragma unroll
            for (int d = 1; d < 16; d <<= 1) m = fmaxf(m, __shfl_xor(m, d, 16));
            const float ex = (lane < 10) ? __expf(sc - m) : 0.f;
            float sum = ex;
#pragma unroll
            for (int d = 1; d < 16; d <<= 1) sum += __shfl_xor(sum, d, 16);
            if (lane < 10) out[(size_t)n * 10 + lane] = ex / sum;
        }
    }
}

extern "C" void kernel_launch(void* const* d_in, const int* in_sizes, int n_in,
                              void* d_out, int out_size, void* d_ws, size_t ws_size,
                              hipStream_t stream)
{
    const float* O    = (const float*)d_in[0];
    const float* X    = (const float*)d_in[1];
    const float* R_a  = (const float*)d_in[2];
    const int* senders   = (const int*)d_in[3];
    const int* receivers = (const int*)d_in[4];
    const float* W_r  = (const float*)d_in[5];
    const float* b_r  = (const float*)d_in[6];
    const float* W_o  = (const float*)d_in[7];
    const float* b_o  = (const float*)d_in[8];
    const float* W_s  = (const float*)d_in[9];
    const float* b_s  = (const float*)d_in[10];
    float* out = (float*)d_out;
    char* ws = (char*)d_ws;

    float* A      = (float*)(ws + WS_A);
    int* bcount   = (int*)(ws + WS_BCOUNT);
    int* bbase    = (int*)(ws + WS_BBASE);
    int* bcur     = (int*)(ws + WS_BCUR);
    float* us     = (float*)(ws + WS_US);
    float* u01    = (float*)(ws + WS_U01);
    unsigned int* pay = (unsigned int*)(ws + WS_PAY);

    hipMemsetAsync(bcount, 0, (size_t)4096, stream);

    precompute_A<<<10, 256, 0, stream>>>(W_r, b_r, W_o, b_o, W_s, b_s, A);

    node_u_kernel<<<(N_NODES * 5 + 255) / 256, 256, 0, stream>>>(O, X, A, us, u01);

    hist_kernel<<<NBLK_E, 256, 0, stream>>>(receivers, bcount);

    scan_kernel<<<1, 64, 0, stream>>>(bcount, bbase, bcur);

    bin_scatter_kernel<<<NBLK_E, 256, 0, stream>>>(
        R_a, senders, receivers, us, A, bcur, pay);

    bin_reduce_kernel<<<NBINS, 1024, 0, stream>>>(pay, bbase, u01, out);
}

// Round 14
// 162.654 us; speedup vs baseline: 1.8375x; 1.8375x over previous
//
#include <hip/hip_runtime.h>

#define N_NODES 50000
#define N_EDGES 800000
// D_S=64, D_R=16, D_E=64, D_X=16, D_P=64, NUM_CLASSES=10
// W_r: [144,64]; W_o: [144,64]; W_s: [64,10] (all row-major)
//
// Linear refactor: scores[n] = u0[n] + deg_n*u1[n] + sum_{e->n} w_e
//   w_e  = u_s[s_e] + R_a[e]@A_R          (computed in EDGE order, streamed)
//   u_s[n] = O[n]@A_S ; u0[n] = O[n]@A_O + X[n]@A_X + c1 ; u1[n] = O[n]@A_dO + c0
// with Wc = W_o@W_s [144,10], Wc2 = Wc[80:144],
//   A_O = Wc[0:64], A_X = Wc[64:80], A_S = W_r[0:64]@Wc2,
//   A_R = W_r[128:144]@Wc2, A_dO = W_r[64:128]@Wc2,
//   c0 = b_r@Wc2, c1 = b_o@W_s + b_s.
//
// r9: only per-edge atomic in count_rank (return value = rank).
// r10: node_u table loads from LDS, vectorized O/X.
// r12: 2 edges/thread does NOT help edge_w (store-bound, ILP-invariant).
// r13: 64-bin LDS reduce = parallelism disaster; reverted.
// r14 (this): scattered record stores via __builtin_nontemporal_store —
// avoid L2 line allocation / cross-XCD dirty-line ping-pong on the 20 B
// scattered writes (HBM handles sub-line writes with byte masks).
//
// A-table layout in ws: [226][16] f32 (cols 10..15 zeroed):
//   rows 0..63 A_O | 64..79 A_X | 80..143 A_S | 144..159 A_R |
//   160..223 A_dO | 224 c0 | 225 c1

// ---------------------------------------------------------------------------
// Workspace layout (bytes) — end = 26,019,328 < 26,414,400 (proven in r3)
// ---------------------------------------------------------------------------
#define WS_A       ((size_t)0)          // 14,464 B
#define WS_COUNT   ((size_t)16384)      // 50000 i32 = 200,000 B
#define WS_CURSOR  ((size_t)216384)     // 1 u32 (zeroed with count memset)
#define WS_OFF     ((size_t)217088)     // 50000 i32 = 200,000 B
#define WS_RANK    ((size_t)417792)     // 800000 i32 = 3,200,000 B
#define WS_US      ((size_t)3618816)    // 50000*12 f32 = 2,400,000 B
#define WS_U01     ((size_t)6019072)    // 50000*20 f32 = 4,000,000 B
#define WS_WSORT   ((size_t)10019328)   // 800000*5 u32 = 16,000,000 B

__device__ __forceinline__ unsigned int f32_to_bf16_rne(float f) {
    unsigned int x = __float_as_uint(f);
    return (x + 0x7fffu + ((x >> 16) & 1u)) >> 16;
}

// ---------------------------------------------------------------------------
// Precompute folded weight table A — 10 blocks, redundant Wc2 in LDS
// ---------------------------------------------------------------------------
__global__ __launch_bounds__(256) void precompute_A(
    const float* __restrict__ W_r, const float* __restrict__ b_r,
    const float* __restrict__ W_o, const float* __restrict__ b_o,
    const float* __restrict__ W_s, const float* __restrict__ b_s,
    float* __restrict__ A)
{
    __shared__ float Wc2[640];  // Wc rows 80..143 (64 x 10)
    const int t = threadIdx.x;

    for (int idx = t; idx < 640; idx += 256) {
        const int row = 80 + idx / 10, c = idx % 10;
        float acc = 0.f;
        for (int j = 0; j < 64; ++j)
            acc = fmaf(W_o[row * 64 + j], W_s[j * 10 + c], acc);
        Wc2[idx] = acc;
    }
    __syncthreads();

    // work items: [0,1356) zero pads | [1356,2156) A_O/A_X | [2156,3596) A_S/A_R/A_dO
    //             [3596,3606) c0 | [3606,3616) c1
    for (int g = blockIdx.x * 256 + t; g < 3616; g += gridDim.x * 256) {
        if (g < 1356) {
            const int row = g / 6, c = 10 + g % 6;
            A[row * 16 + c] = 0.f;
        } else if (g < 2156) {
            const int i = g - 1356, row = i / 10, c = i % 10;
            float acc = 0.f;
            for (int j = 0; j < 64; ++j)
                acc = fmaf(W_o[row * 64 + j], W_s[j * 10 + c], acc);
            A[row * 16 + c] = acc;
        } else if (g < 3596) {
            const int i = g - 2156, k = i / 10, c = i % 10;
            const int wrow = (k < 64) ? k : (k < 80 ? 128 + (k - 64) : 64 + (k - 80));
            const int arow = (k < 64) ? 80 + k : (k < 80 ? 144 + (k - 64) : 160 + (k - 80));
            const float* src = W_r + (size_t)wrow * 64;
            float acc = 0.f;
            for (int m = 0; m < 64; ++m)
                acc = fmaf(src[m], Wc2[m * 10 + c], acc);
            A[arow * 16 + c] = acc;
        } else if (g < 3606) {
            const int c = g - 3596;
            float acc = 0.f;
            for (int m = 0; m < 64; ++m)
                acc = fmaf(b_r[m], Wc2[m * 10 + c], acc);
            A[224 * 16 + c] = acc;
        } else {
            const int c = g - 3606;
            float acc = b_s[c];
            for (int j = 0; j < 64; ++j)
                acc = fmaf(b_o[j], W_s[j * 10 + c], acc);
            A[225 * 16 + c] = acc;
        }
    }
}

// ---------------------------------------------------------------------------
// Per-node 10-vectors (r10 structure): thread = (node, class-PAIR),
// A staged in LDS as float2 pairs, O/X read as float4.
// ---------------------------------------------------------------------------
__global__ __launch_bounds__(256) void node_u_kernel(
    const float* __restrict__ O, const float* __restrict__ X,
    const float* __restrict__ A,
    float* __restrict__ us, float* __restrict__ u01)
{
    __shared__ float2 lA[226 * 5];  // lA[row*5+cp] = (A[row][2cp], A[row][2cp+1])
    const int t = threadIdx.x;
    for (int i = t; i < 226 * 5; i += 256) {
        const int row = i / 5, cp = i - row * 5;
        lA[i] = *reinterpret_cast<const float2*>(A + (size_t)row * 16 + 2 * cp);
    }
    __syncthreads();

    const int tid = blockIdx.x * 256 + t;
    if (tid >= N_NODES * 5) return;
    const int n = tid / 5;
    const int cp = tid - n * 5;

    float vs0 = 0.f, vs1 = 0.f, v00 = 0.f, v01 = 0.f, v10 = 0.f, v11 = 0.f;

    const float4* Ov = reinterpret_cast<const float4*>(O + (size_t)n * 64);
#pragma unroll
    for (int kc = 0; kc < 16; ++kc) {
        const float4 o4 = Ov[kc];
#pragma unroll
        for (int j = 0; j < 4; ++j) {
            const float ov = (j == 0) ? o4.x : (j == 1) ? o4.y : (j == 2) ? o4.z : o4.w;
            const int k = kc * 4 + j;
            const float2 aO = lA[k * 5 + cp];            // A_O row k
            const float2 aS = lA[(80 + k) * 5 + cp];     // A_S row k
            const float2 aD = lA[(160 + k) * 5 + cp];    // A_dO row k
            v00 = fmaf(ov, aO.x, v00); v01 = fmaf(ov, aO.y, v01);
            vs0 = fmaf(ov, aS.x, vs0); vs1 = fmaf(ov, aS.y, vs1);
            v10 = fmaf(ov, aD.x, v10); v11 = fmaf(ov, aD.y, v11);
        }
    }
    const float4* Xv = reinterpret_cast<const float4*>(X + (size_t)n * 16);
#pragma unroll
    for (int kc = 0; kc < 4; ++kc) {
        const float4 x4 = Xv[kc];
#pragma unroll
        for (int j = 0; j < 4; ++j) {
            const float xv = (j == 0) ? x4.x : (j == 1) ? x4.y : (j == 2) ? x4.z : x4.w;
            const int k = 64 + kc * 4 + j;
            const float2 aX = lA[k * 5 + cp];            // A_X row
            v00 = fmaf(xv, aX.x, v00); v01 = fmaf(xv, aX.y, v01);
        }
    }

    const float2 c0 = lA[224 * 5 + cp];
    const float2 c1 = lA[225 * 5 + cp];
    *reinterpret_cast<float2*>(us + (size_t)n * 12 + 2 * cp) = make_float2(vs0, vs1);
    *reinterpret_cast<float2*>(u01 + (size_t)n * 20 + 2 * cp) =
        make_float2(v00 + c1.x, v01 + c1.y);
    *reinterpret_cast<float2*>(u01 + (size_t)n * 20 + 10 + 2 * cp) =
        make_float2(v10 + c0.x, v11 + c0.y);
}

// ---------------------------------------------------------------------------
// Receiver histogram + rank: the atomic's return value IS the rank.
// ---------------------------------------------------------------------------
__global__ __launch_bounds__(256) void count_rank_kernel(
    const int* __restrict__ receivers, int* __restrict__ count,
    int* __restrict__ rank)
{
    const int t = blockIdx.x * 256 + threadIdx.x;
    if (t * 4 >= N_EDGES) return;
    const int4 r4 = reinterpret_cast<const int4*>(receivers)[t];
    int4 k4;
    k4.x = atomicAdd(count + r4.x, 1);
    k4.y = atomicAdd(count + r4.y, 1);
    k4.z = atomicAdd(count + r4.z, 1);
    k4.w = atomicAdd(count + r4.w, 1);
    reinterpret_cast<int4*>(rank)[t] = k4;
}

// ---------------------------------------------------------------------------
// Segment allocation, wave-aggregated: shfl prefix-sum, 1 atomic per wave.
// ---------------------------------------------------------------------------
__global__ __launch_bounds__(256) void alloc_kernel(
    const int* __restrict__ count, unsigned int* __restrict__ cursor,
    int* __restrict__ off)
{
    const int n = blockIdx.x * 256 + threadIdx.x;
    const int lane = threadIdx.x & 63;
    const int c = (n < N_NODES) ? count[n] : 0;

    int pre = c;
#pragma unroll
    for (int d = 1; d < 64; d <<= 1) {
        const int v = __shfl_up(pre, d);
        if (lane >= d) pre += v;
    }
    const int total = __shfl(pre, 63);
    int base = 0;
    if (lane == 63) base = (int)atomicAdd(cursor, (unsigned int)total);
    base = __shfl(base, 63);

    if (n < N_NODES) off[n] = base + pre - c;  // exclusive prefix
}

// ---------------------------------------------------------------------------
// Per-edge w_e = u_s[s_e] + R_a[e]@A_R -> bf16-packed, written directly to
// receiver-sorted slot pos = off[r] + rank[e]. No atomic. Scattered stores
// are NON-TEMPORAL: no L2 line allocation -> no cross-XCD RMW ping-pong.
// ---------------------------------------------------------------------------
__global__ __launch_bounds__(256) void edge_w_kernel(
    const float* __restrict__ R_a,
    const int* __restrict__ senders, const int* __restrict__ receivers,
    const int* __restrict__ rank, const int* __restrict__ off,
    const float* __restrict__ us, const float* __restrict__ A,
    unsigned int* __restrict__ wsort)   // [E][5] dwords, receiver-sorted
{
    const int e = blockIdx.x * blockDim.x + threadIdx.x;
    if (e >= N_EDGES) return;
    const int s = senders[e];
    const int r = receivers[e];
    const int pos = off[r] + rank[e];   // plain loads — no atomic

    // u_s[s]: 48 B gather from L2-resident 2.4 MB table (cached — NOT nt)
    const float4* U = reinterpret_cast<const float4*>(us + (size_t)s * 12);
    const float4 ua = U[0];
    const float4 ub = U[1];
    const float4 uc = U[2];
    float a[10] = {ua.x, ua.y, ua.z, ua.w, ub.x, ub.y, ub.z, ub.w, uc.x, uc.y};

    // R_a[e] @ A_R (A rows 144..159) — R_a streamed coalesced
    const float4* Rv = reinterpret_cast<const float4*>(R_a + (size_t)e * 16);
#pragma unroll
    for (int kc = 0; kc < 4; ++kc) {
        const float4 b4 = Rv[kc];
        const float* A0 = A + (size_t)(144 + kc * 4) * 16;
#pragma unroll
        for (int c = 0; c < 10; ++c) a[c] = fmaf(b4.x, A0[c], a[c]);
#pragma unroll
        for (int c = 0; c < 10; ++c) a[c] = fmaf(b4.y, A0[16 + c], a[c]);
#pragma unroll
        for (int c = 0; c < 10; ++c) a[c] = fmaf(b4.z, A0[32 + c], a[c]);
#pragma unroll
        for (int c = 0; c < 10; ++c) a[c] = fmaf(b4.w, A0[48 + c], a[c]);
    }

    unsigned int* wp = wsort + (size_t)pos * 5;
    __builtin_nontemporal_store(
        f32_to_bf16_rne(a[0]) | (f32_to_bf16_rne(a[1]) << 16), wp + 0);
    __builtin_nontemporal_store(
        f32_to_bf16_rne(a[2]) | (f32_to_bf16_rne(a[3]) << 16), wp + 1);
    __builtin_nontemporal_store(
        f32_to_bf16_rne(a[4]) | (f32_to_bf16_rne(a[5]) << 16), wp + 2);
    __builtin_nontemporal_store(
        f32_to_bf16_rne(a[6]) | (f32_to_bf16_rne(a[7]) << 16), wp + 3);
    __builtin_nontemporal_store(
        f32_to_bf16_rne(a[8]) | (f32_to_bf16_rne(a[9]) << 16), wp + 4);
}

// ---------------------------------------------------------------------------
// Node scores: thread = (node, class-slot c<16). w read as a PURE SEQUENTIAL
// stream with nt loads (read-once; don't evict u_s/u01 from L2).
// ---------------------------------------------------------------------------
__global__ __launch_bounds__(256) void node_score_kernel(
    const float* __restrict__ u01,
    const int* __restrict__ off, const int* __restrict__ count,
    const unsigned int* __restrict__ w,   // [E][5] dwords, receiver-sorted
    float* __restrict__ out)
{
    const int tid = blockIdx.x * 256 + threadIdx.x;
    const int n = tid >> 4;
    const int c = tid & 15;
    if (n >= N_NODES) return;

    const int cc = (c < 10) ? c : 0;  // safe column for idle lanes
    const int half = cc >> 1;
    const int sh = (cc & 1) * 16;

    const int beg = off[n];
    const int dge = count[n];
    const int end = beg + dge;
    float sc = u01[(size_t)n * 20 + cc] + (float)dge * u01[(size_t)n * 20 + 10 + cc];

    float s0 = 0.f, s1 = 0.f, s2 = 0.f, s3 = 0.f;
    int i = beg;
    for (; i + 3 < end; i += 4) {
        const unsigned int v0 = __builtin_nontemporal_load(w + (size_t)(i + 0) * 5 + half);
        const unsigned int v1 = __builtin_nontemporal_load(w + (size_t)(i + 1) * 5 + half);
        const unsigned int v2 = __builtin_nontemporal_load(w + (size_t)(i + 2) * 5 + half);
        const unsigned int v3 = __builtin_nontemporal_load(w + (size_t)(i + 3) * 5 + half);
        s0 += __uint_as_float((v0 >> sh) << 16);
        s1 += __uint_as_float((v1 >> sh) << 16);
        s2 += __uint_as_float((v2 >> sh) << 16);
        s3 += __uint_as_float((v3 >> sh) << 16);
    }
    for (; i < end; ++i) {
        const unsigned int v = __builtin_nontemporal_load(w + (size_t)i * 5 + half);
        s0 += __uint_as_float((v >> sh) << 16);
    }
    sc += (s0 + s1) + (s2 + s3);

    // softmax over the 10 active lanes of this 16-lane group
    float m = (c < 10) ? sc : -3.0e38f;
#pragma unroll
    for (int d = 1; d < 16; d <<= 1) m = fmaxf(m, __shfl_xor(m, d, 16));
    const float ex = (c < 10) ? __expf(sc - m) : 0.f;
    float sum = ex;
#pragma unroll
    for (int d = 1; d < 16; d <<= 1) sum += __shfl_xor(sum, d, 16);
    if (c < 10) out[(size_t)n * 10 + c] = ex / sum;
}

extern "C" void kernel_launch(void* const* d_in, const int* in_sizes, int n_in,
                              void* d_out, int out_size, void* d_ws, size_t ws_size,
                              hipStream_t stream)
{
    const float* O    = (const float*)d_in[0];
    const float* X    = (const float*)d_in[1];
    const float* R_a  = (const float*)d_in[2];
    const int* senders   = (const int*)d_in[3];
    const int* receivers = (const int*)d_in[4];
    const float* W_r  = (const float*)d_in[5];
    const float* b_r  = (const float*)d_in[6];
    const float* W_o  = (const float*)d_in[7];
    const float* b_o  = (const float*)d_in[8];
    const float* W_s  = (const float*)d_in[9];
    const float* b_s  = (const float*)d_in[10];
    float* out = (float*)d_out;
    char* ws = (char*)d_ws;

    float* A      = (float*)(ws + WS_A);
    int* count    = (int*)(ws + WS_COUNT);
    unsigned int* cursor = (unsigned int*)(ws + WS_CURSOR);
    int* off      = (int*)(ws + WS_OFF);
    int* rank     = (int*)(ws + WS_RANK);
    float* us     = (float*)(ws + WS_US);
    float* u01    = (float*)(ws + WS_U01);
    unsigned int* wsort = (unsigned int*)(ws + WS_WSORT);

    // zero count histogram + cursor (adjacent) in one memset
    hipMemsetAsync(count, 0, (size_t)(200000 + 4 + 384), stream);

    precompute_A<<<10, 256, 0, stream>>>(W_r, b_r, W_o, b_o, W_s, b_s, A);

    count_rank_kernel<<<(N_EDGES / 4 + 255) / 256, 256, 0, stream>>>(
        receivers, count, rank);

    alloc_kernel<<<(N_NODES + 255) / 256, 256, 0, stream>>>(count, cursor, off);

    node_u_kernel<<<(N_NODES * 5 + 255) / 256, 256, 0, stream>>>(O, X, A, us, u01);

    edge_w_kernel<<<(N_EDGES + 255) / 256, 256, 0, stream>>>(
        R_a, senders, receivers, rank, off, us, A, wsort);

    node_score_kernel<<<(N_NODES * 16 + 255) / 256, 256, 0, stream>>>(
        u01, off, count, wsort, out);
}

// Round 15
// 125.263 us; speedup vs baseline: 2.3860x; 1.2985x over previous
//
#include <hip/hip_runtime.h>

#define N_NODES 50000
#define N_EDGES 800000
// D_S=64, D_R=16, D_E=64, D_X=16, D_P=64, NUM_CLASSES=10
// W_r: [144,64]; W_o: [144,64]; W_s: [64,10] (all row-major)
//
// Linear refactor: scores[n] = u0[n] + deg_n*u1[n] + sum_{e->n} w_e
//   w_e  = u_s[s_e] + R_a[e]@A_R          (computed in EDGE order, streamed)
//   u_s[n] = O[n]@A_S ; u0[n] = O[n]@A_O + X[n]@A_X + c1 ; u1[n] = O[n]@A_dO + c0
// with Wc = W_o@W_s [144,10], Wc2 = Wc[80:144],
//   A_O = Wc[0:64], A_X = Wc[64:80], A_S = W_r[0:64]@Wc2,
//   A_R = W_r[128:144]@Wc2, A_dO = W_r[64:128]@Wc2,
//   c0 = b_r@Wc2, c1 = b_o@W_s + b_s.
//
// r9: only per-edge atomic in count_rank (return value = rank).
// r10: node_u table loads from LDS, vectorized O/X.
// r12: 2 edges/thread does NOT help edge_w (store-bound, ILP-invariant).
// r13: 64-bin LDS reduce = parallelism disaster; reverted.
// r14: nt stores REGRESSED (bypass L2 merge -> sub-line HBM writes); plain
//      stores restored. Scatter cost = #random lines touched; ~53 us floor.
// r15 (this): node_score was a hidden ~40 us, load-issue-bound on 4 B
//      strided loads. Consecutive nodes have ADJACENT wsort segments
//      (alloc prefix is node-ordered within each 64-node wave chunk), so a
//      16-node block streams its contiguous range into LDS coalesced, then
//      reduces from LDS.
//
// A-table layout in ws: [226][16] f32 (cols 10..15 zeroed):
//   rows 0..63 A_O | 64..79 A_X | 80..143 A_S | 144..159 A_R |
//   160..223 A_dO | 224 c0 | 225 c1

// ---------------------------------------------------------------------------
// Workspace layout (bytes) — end = 26,019,328 < 26,414,400 (proven in r3)
// ---------------------------------------------------------------------------
#define WS_A       ((size_t)0)          // 14,464 B
#define WS_COUNT   ((size_t)16384)      // 50000 i32 = 200,000 B
#define WS_CURSOR  ((size_t)216384)     // 1 u32 (zeroed with count memset)
#define WS_OFF     ((size_t)217088)     // 50000 i32 = 200,000 B
#define WS_RANK    ((size_t)417792)     // 800000 i32 = 3,200,000 B
#define WS_US      ((size_t)3618816)    // 50000*12 f32 = 2,400,000 B
#define WS_U01     ((size_t)6019072)    // 50000*20 f32 = 4,000,000 B
#define WS_WSORT   ((size_t)10019328)   // 800000*5 u32 = 16,000,000 B

__device__ __forceinline__ unsigned int f32_to_bf16_rne(float f) {
    unsigned int x = __float_as_uint(f);
    return (x + 0x7fffu + ((x >> 16) & 1u)) >> 16;
}

// ---------------------------------------------------------------------------
// Precompute folded weight table A — 10 blocks, redundant Wc2 in LDS
// ---------------------------------------------------------------------------
__global__ __launch_bounds__(256) void precompute_A(
    const float* __restrict__ W_r, const float* __restrict__ b_r,
    const float* __restrict__ W_o, const float* __restrict__ b_o,
    const float* __restrict__ W_s, const float* __restrict__ b_s,
    float* __restrict__ A)
{
    __shared__ float Wc2[640];  // Wc rows 80..143 (64 x 10)
    const int t = threadIdx.x;

    for (int idx = t; idx < 640; idx += 256) {
        const int row = 80 + idx / 10, c = idx % 10;
        float acc = 0.f;
        for (int j = 0; j < 64; ++j)
            acc = fmaf(W_o[row * 64 + j], W_s[j * 10 + c], acc);
        Wc2[idx] = acc;
    }
    __syncthreads();

    for (int g = blockIdx.x * 256 + t; g < 3616; g += gridDim.x * 256) {
        if (g < 1356) {
            const int row = g / 6, c = 10 + g % 6;
            A[row * 16 + c] = 0.f;
        } else if (g < 2156) {
            const int i = g - 1356, row = i / 10, c = i % 10;
            float acc = 0.f;
            for (int j = 0; j < 64; ++j)
                acc = fmaf(W_o[row * 64 + j], W_s[j * 10 + c], acc);
            A[row * 16 + c] = acc;
        } else if (g < 3596) {
            const int i = g - 2156, k = i / 10, c = i % 10;
            const int wrow = (k < 64) ? k : (k < 80 ? 128 + (k - 64) : 64 + (k - 80));
            const int arow = (k < 64) ? 80 + k : (k < 80 ? 144 + (k - 64) : 160 + (k - 80));
            const float* src = W_r + (size_t)wrow * 64;
            float acc = 0.f;
            for (int m = 0; m < 64; ++m)
                acc = fmaf(src[m], Wc2[m * 10 + c], acc);
            A[arow * 16 + c] = acc;
        } else if (g < 3606) {
            const int c = g - 3596;
            float acc = 0.f;
            for (int m = 0; m < 64; ++m)
                acc = fmaf(b_r[m], Wc2[m * 10 + c], acc);
            A[224 * 16 + c] = acc;
        } else {
            const int c = g - 3606;
            float acc = b_s[c];
            for (int j = 0; j < 64; ++j)
                acc = fmaf(b_o[j], W_s[j * 10 + c], acc);
            A[225 * 16 + c] = acc;
        }
    }
}

// ---------------------------------------------------------------------------
// Per-node 10-vectors (r10 structure): thread = (node, class-PAIR),
// A staged in LDS as float2 pairs, O/X read as float4.
// ---------------------------------------------------------------------------
__global__ __launch_bounds__(256) void node_u_kernel(
    const float* __restrict__ O, const float* __restrict__ X,
    const float* __restrict__ A,
    float* __restrict__ us, float* __restrict__ u01)
{
    __shared__ float2 lA[226 * 5];  // lA[row*5+cp] = (A[row][2cp], A[row][2cp+1])
    const int t = threadIdx.x;
    for (int i = t; i < 226 * 5; i += 256) {
        const int row = i / 5, cp = i - row * 5;
        lA[i] = *reinterpret_cast<const float2*>(A + (size_t)row * 16 + 2 * cp);
    }
    __syncthreads();

    const int tid = blockIdx.x * 256 + t;
    if (tid >= N_NODES * 5) return;
    const int n = tid / 5;
    const int cp = tid - n * 5;

    float vs0 = 0.f, vs1 = 0.f, v00 = 0.f, v01 = 0.f, v10 = 0.f, v11 = 0.f;

    const float4* Ov = reinterpret_cast<const float4*>(O + (size_t)n * 64);
#pragma unroll
    for (int kc = 0; kc < 16; ++kc) {
        const float4 o4 = Ov[kc];
#pragma unroll
        for (int j = 0; j < 4; ++j) {
            const float ov = (j == 0) ? o4.x : (j == 1) ? o4.y : (j == 2) ? o4.z : o4.w;
            const int k = kc * 4 + j;
            const float2 aO = lA[k * 5 + cp];            // A_O row k
            const float2 aS = lA[(80 + k) * 5 + cp];     // A_S row k
            const float2 aD = lA[(160 + k) * 5 + cp];    // A_dO row k
            v00 = fmaf(ov, aO.x, v00); v01 = fmaf(ov, aO.y, v01);
            vs0 = fmaf(ov, aS.x, vs0); vs1 = fmaf(ov, aS.y, vs1);
            v10 = fmaf(ov, aD.x, v10); v11 = fmaf(ov, aD.y, v11);
        }
    }
    const float4* Xv = reinterpret_cast<const float4*>(X + (size_t)n * 16);
#pragma unroll
    for (int kc = 0; kc < 4; ++kc) {
        const float4 x4 = Xv[kc];
#pragma unroll
        for (int j = 0; j < 4; ++j) {
            const float xv = (j == 0) ? x4.x : (j == 1) ? x4.y : (j == 2) ? x4.z : x4.w;
            const int k = 64 + kc * 4 + j;
            const float2 aX = lA[k * 5 + cp];            // A_X row
            v00 = fmaf(xv, aX.x, v00); v01 = fmaf(xv, aX.y, v01);
        }
    }

    const float2 c0 = lA[224 * 5 + cp];
    const float2 c1 = lA[225 * 5 + cp];
    *reinterpret_cast<float2*>(us + (size_t)n * 12 + 2 * cp) = make_float2(vs0, vs1);
    *reinterpret_cast<float2*>(u01 + (size_t)n * 20 + 2 * cp) =
        make_float2(v00 + c1.x, v01 + c1.y);
    *reinterpret_cast<float2*>(u01 + (size_t)n * 20 + 10 + 2 * cp) =
        make_float2(v10 + c0.x, v11 + c0.y);
}

// ---------------------------------------------------------------------------
// Receiver histogram + rank: the atomic's return value IS the rank.
// ---------------------------------------------------------------------------
__global__ __launch_bounds__(256) void count_rank_kernel(
    const int* __restrict__ receivers, int* __restrict__ count,
    int* __restrict__ rank)
{
    const int t = blockIdx.x * 256 + threadIdx.x;
    if (t * 4 >= N_EDGES) return;
    const int4 r4 = reinterpret_cast<const int4*>(receivers)[t];
    int4 k4;
    k4.x = atomicAdd(count + r4.x, 1);
    k4.y = atomicAdd(count + r4.y, 1);
    k4.z = atomicAdd(count + r4.z, 1);
    k4.w = atomicAdd(count + r4.w, 1);
    reinterpret_cast<int4*>(rank)[t] = k4;
}

// ---------------------------------------------------------------------------
// Segment allocation, wave-aggregated: shfl prefix-sum, 1 atomic per wave.
// NOTE: prefix is node-ordered WITHIN each 64-node wave chunk -> any 16-node
// aligned sub-block owns a contiguous wsort range (used by node_score).
// ---------------------------------------------------------------------------
__global__ __launch_bounds__(256) void alloc_kernel(
    const int* __restrict__ count, unsigned int* __restrict__ cursor,
    int* __restrict__ off)
{
    const int n = blockIdx.x * 256 + threadIdx.x;
    const int lane = threadIdx.x & 63;
    const int c = (n < N_NODES) ? count[n] : 0;

    int pre = c;
#pragma unroll
    for (int d = 1; d < 64; d <<= 1) {
        const int v = __shfl_up(pre, d);
        if (lane >= d) pre += v;
    }
    const int total = __shfl(pre, 63);
    int base = 0;
    if (lane == 63) base = (int)atomicAdd(cursor, (unsigned int)total);
    base = __shfl(base, 63);

    if (n < N_NODES) off[n] = base + pre - c;  // exclusive prefix
}

// ---------------------------------------------------------------------------
// Per-edge w_e = u_s[s_e] + R_a[e]@A_R -> bf16-packed, written directly to
// receiver-sorted slot pos = off[r] + rank[e]. No atomic. Plain stores
// (r14: nt stores regressed — keep L2's RMW merge).
// ---------------------------------------------------------------------------
__global__ __launch_bounds__(256) void edge_w_kernel(
    const float* __restrict__ R_a,
    const int* __restrict__ senders, const int* __restrict__ receivers,
    const int* __restrict__ rank, const int* __restrict__ off,
    const float* __restrict__ us, const float* __restrict__ A,
    unsigned int* __restrict__ wsort)   // [E][5] dwords, receiver-sorted
{
    const int e = blockIdx.x * blockDim.x + threadIdx.x;
    if (e >= N_EDGES) return;
    const int s = senders[e];
    const int r = receivers[e];
    const int pos = off[r] + rank[e];   // plain loads — no atomic

    // u_s[s]: 48 B gather from L2-resident 2.4 MB table
    const float4* U = reinterpret_cast<const float4*>(us + (size_t)s * 12);
    const float4 ua = U[0];
    const float4 ub = U[1];
    const float4 uc = U[2];
    float a[10] = {ua.x, ua.y, ua.z, ua.w, ub.x, ub.y, ub.z, ub.w, uc.x, uc.y};

    // R_a[e] @ A_R (A rows 144..159) — R_a streamed coalesced
    const float4* Rv = reinterpret_cast<const float4*>(R_a + (size_t)e * 16);
#pragma unroll
    for (int kc = 0; kc < 4; ++kc) {
        const float4 b4 = Rv[kc];
        const float* A0 = A + (size_t)(144 + kc * 4) * 16;
#pragma unroll
        for (int c = 0; c < 10; ++c) a[c] = fmaf(b4.x, A0[c], a[c]);
#pragma unroll
        for (int c = 0; c < 10; ++c) a[c] = fmaf(b4.y, A0[16 + c], a[c]);
#pragma unroll
        for (int c = 0; c < 10; ++c) a[c] = fmaf(b4.z, A0[32 + c], a[c]);
#pragma unroll
        for (int c = 0; c < 10; ++c) a[c] = fmaf(b4.w, A0[48 + c], a[c]);
    }

    unsigned int* wp = wsort + (size_t)pos * 5;
    wp[0] = f32_to_bf16_rne(a[0]) | (f32_to_bf16_rne(a[1]) << 16);
    wp[1] = f32_to_bf16_rne(a[2]) | (f32_to_bf16_rne(a[3]) << 16);
    wp[2] = f32_to_bf16_rne(a[4]) | (f32_to_bf16_rne(a[5]) << 16);
    wp[3] = f32_to_bf16_rne(a[6]) | (f32_to_bf16_rne(a[7]) << 16);
    wp[4] = f32_to_bf16_rne(a[8]) | (f32_to_bf16_rne(a[9]) << 16);
}

// ---------------------------------------------------------------------------
// Node scores (r15): block = 16 aligned nodes = one CONTIGUOUS wsort range.
// Stream range into LDS with coalesced dword loads (512-record chunks),
// then 16-lane groups reduce from LDS. Head + softmax fused.
// ---------------------------------------------------------------------------
#define CH_REC 512   // records per LDS chunk (2560 dwords = 10,240 B)

__global__ __launch_bounds__(256) void node_score_kernel(
    const float* __restrict__ u01,
    const int* __restrict__ off, const int* __restrict__ count,
    const unsigned int* __restrict__ w,   // [E][5] dwords, receiver-sorted
    float* __restrict__ out)
{
    __shared__ unsigned int lw[CH_REC * 5];
    const int t = threadIdx.x;
    const int n0 = blockIdx.x * 16;        // 16 | 64 -> block range contiguous
    const int g = t >> 4;                  // group 0..15 -> node n0+g
    const int lane = t & 15;
    const int n = n0 + g;                  // N_NODES % 16 == 0: always valid

    const int beg16 = off[n0];
    const int end16 = off[n0 + 15] + count[n0 + 15];

    const int beg = off[n];
    const int cnt = count[n];
    const int dge = cnt;

    const int cc = (lane < 10) ? lane : 0;
    const int half = cc >> 1;
    const int sh = (cc & 1) * 16;

    float sc = u01[(size_t)n * 20 + cc] + (float)dge * u01[(size_t)n * 20 + 10 + cc];

    for (int c0 = beg16; c0 < end16; c0 += CH_REC) {
        const int nrec = min(CH_REC, end16 - c0);
        const int ndw = nrec * 5;
        __syncthreads();
        for (int i = t; i < ndw; i += 256)
            lw[i] = w[(size_t)c0 * 5 + i];
        __syncthreads();

        // this node's records inside the chunk
        const int j0 = max(beg, c0);
        const int j1 = min(beg + cnt, c0 + nrec);
        for (int j = j0; j < j1; ++j) {
            const unsigned int v = lw[(j - c0) * 5 + half];
            sc += __uint_as_float((v >> sh) << 16);
        }
    }

    // softmax over the 10 active lanes of this 16-lane group
    float m = (lane < 10) ? sc : -3.0e38f;
#pragma unroll
    for (int d = 1; d < 16; d <<= 1) m = fmaxf(m, __shfl_xor(m, d, 16));
    const float ex = (lane < 10) ? __expf(sc - m) : 0.f;
    float sum = ex;
#pragma unroll
    for (int d = 1; d < 16; d <<= 1) sum += __shfl_xor(sum, d, 16);
    if (lane < 10) out[(size_t)n * 10 + lane] = ex / sum;
}

extern "C" void kernel_launch(void* const* d_in, const int* in_sizes, int n_in,
                              void* d_out, int out_size, void* d_ws, size_t ws_size,
                              hipStream_t stream)
{
    const float* O    = (const float*)d_in[0];
    const float* X    = (const float*)d_in[1];
    const float* R_a  = (const float*)d_in[2];
    const int* senders   = (const int*)d_in[3];
    const int* receivers = (const int*)d_in[4];
    const float* W_r  = (const float*)d_in[5];
    const float* b_r  = (const float*)d_in[6];
    const float* W_o  = (const float*)d_in[7];
    const float* b_o  = (const float*)d_in[8];
    const float* W_s  = (const float*)d_in[9];
    const float* b_s  = (const float*)d_in[10];
    float* out = (float*)d_out;
    char* ws = (char*)d_ws;

    float* A      = (float*)(ws + WS_A);
    int* count    = (int*)(ws + WS_COUNT);
    unsigned int* cursor = (unsigned int*)(ws + WS_CURSOR);
    int* off      = (int*)(ws + WS_OFF);
    int* rank     = (int*)(ws + WS_RANK);
    float* us     = (float*)(ws + WS_US);
    float* u01    = (float*)(ws + WS_U01);
    unsigned int* wsort = (unsigned int*)(ws + WS_WSORT);

    // zero count histogram + cursor (adjacent) in one memset
    hipMemsetAsync(count, 0, (size_t)(200000 + 4 + 384), stream);

    precompute_A<<<10, 256, 0, stream>>>(W_r, b_r, W_o, b_o, W_s, b_s, A);

    count_rank_kernel<<<(N_EDGES / 4 + 255) / 256, 256, 0, stream>>>(
        receivers, count, rank);

    alloc_kernel<<<(N_NODES + 255) / 256, 256, 0, stream>>>(count, cursor, off);

    node_u_kernel<<<(N_NODES * 5 + 255) / 256, 256, 0, stream>>>(O, X, A, us, u01);

    edge_w_kernel<<<(N_EDGES + 255) / 256, 256, 0, stream>>>(
        R_a, senders, receivers, rank, off, us, A, wsort);

    node_score_kernel<<<N_NODES / 16, 256, 0, stream>>>(
        u01, off, count, wsort, out);
}

// Round 16
// 116.481 us; speedup vs baseline: 2.5659x; 1.0754x over previous
//
#include <hip/hip_runtime.h>

#define N_NODES 50000
#define N_EDGES 800000
// D_S=64, D_R=16, D_E=64, D_X=16, D_P=64, NUM_CLASSES=10
// W_r: [144,64]; W_o: [144,64]; W_s: [64,10] (all row-major)
//
// Linear refactor: scores[n] = u0[n] + deg_n*u1[n] + sum_{e->n} w_e
//   w_e  = u_s[s_e] + R_a[e]@A_R          (computed in EDGE order, streamed)
//   u_s[n] = O[n]@A_S ; u0[n] = O[n]@A_O + X[n]@A_X + c1 ; u1[n] = O[n]@A_dO + c0
// with Wc = W_o@W_s [144,10], Wc2 = Wc[80:144],
//   A_O = Wc[0:64], A_X = Wc[64:80], A_S = W_r[0:64]@Wc2,
//   A_R = W_r[128:144]@Wc2, A_dO = W_r[64:128]@Wc2,
//   c0 = b_r@Wc2, c1 = b_o@W_s + b_s.
//
// r9: only per-edge atomic in count_rank (return value = rank).
// r10: node_u table loads from LDS, vectorized O/X.
// r12: more ILP does NOT help edge_w (store-bound, ILP-invariant).
// r13: 64-bin LDS reduce = parallelism disaster.
// r14: nt stores regressed (L2 RMW merge was helping). edge_w ~52 us floor.
// r15: node_score LDS-chunked (neutral; kept — strictly better structure).
// r16 (this): FUSION. ~25 us of wall time was serial dispatch gaps. DAG
// pairs {precompute_A || count_rank} and {alloc || node_u} are independent;
// fuse via blockIdx partition. 7 dispatches -> 5. Kernel bodies unchanged.
//
// A-table layout in ws: [226][16] f32 (cols 10..15 zeroed):
//   rows 0..63 A_O | 64..79 A_X | 80..143 A_S | 144..159 A_R |
//   160..223 A_dO | 224 c0 | 225 c1

// ---------------------------------------------------------------------------
// Workspace layout (bytes) — end = 26,019,328 < 26,414,400 (proven in r3)
// ---------------------------------------------------------------------------
#define WS_A       ((size_t)0)          // 14,464 B
#define WS_COUNT   ((size_t)16384)      // 50000 i32 = 200,000 B
#define WS_CURSOR  ((size_t)216384)     // 1 u32 (zeroed with count memset)
#define WS_OFF     ((size_t)217088)     // 50000 i32 = 200,000 B
#define WS_RANK    ((size_t)417792)     // 800000 i32 = 3,200,000 B
#define WS_US      ((size_t)3618816)    // 50000*12 f32 = 2,400,000 B
#define WS_U01     ((size_t)6019072)    // 50000*20 f32 = 4,000,000 B
#define WS_WSORT   ((size_t)10019328)   // 800000*5 u32 = 16,000,000 B

#define NB_PRE   10                     // precompute_A blocks
#define NB_CR    ((N_EDGES / 4 + 255) / 256)        // 782 count_rank blocks
#define NB_ALLOC ((N_NODES + 255) / 256)            // 196 alloc blocks
#define NB_NU    ((N_NODES * 5 + 255) / 256)        // 977 node_u blocks

__device__ __forceinline__ unsigned int f32_to_bf16_rne(float f) {
    unsigned int x = __float_as_uint(f);
    return (x + 0x7fffu + ((x >> 16) & 1u)) >> 16;
}

// ---------------------------------------------------------------------------
// Fused K1: blocks [0,NB_PRE) precompute A; blocks [NB_PRE,..) count+rank.
// Independent outputs (A vs count/rank) — safe to co-dispatch.
// ---------------------------------------------------------------------------
__global__ __launch_bounds__(256) void fused_prep_kernel(
    const float* __restrict__ W_r, const float* __restrict__ b_r,
    const float* __restrict__ W_o, const float* __restrict__ b_o,
    const float* __restrict__ W_s, const float* __restrict__ b_s,
    const int* __restrict__ receivers,
    float* __restrict__ A, int* __restrict__ count, int* __restrict__ rank)
{
    __shared__ float Wc2[640];  // used by precompute role only
    const int t = threadIdx.x;

    if (blockIdx.x < NB_PRE) {
        // ---- precompute_A role (grid-stride over NB_PRE blocks) ----
        for (int idx = t; idx < 640; idx += 256) {
            const int row = 80 + idx / 10, c = idx % 10;
            float acc = 0.f;
            for (int j = 0; j < 64; ++j)
                acc = fmaf(W_o[row * 64 + j], W_s[j * 10 + c], acc);
            Wc2[idx] = acc;
        }
        __syncthreads();

        for (int g = blockIdx.x * 256 + t; g < 3616; g += NB_PRE * 256) {
            if (g < 1356) {
                const int row = g / 6, c = 10 + g % 6;
                A[row * 16 + c] = 0.f;
            } else if (g < 2156) {
                const int i = g - 1356, row = i / 10, c = i % 10;
                float acc = 0.f;
                for (int j = 0; j < 64; ++j)
                    acc = fmaf(W_o[row * 64 + j], W_s[j * 10 + c], acc);
                A[row * 16 + c] = acc;
            } else if (g < 3596) {
                const int i = g - 2156, k = i / 10, c = i % 10;
                const int wrow = (k < 64) ? k : (k < 80 ? 128 + (k - 64) : 64 + (k - 80));
                const int arow = (k < 64) ? 80 + k : (k < 80 ? 144 + (k - 64) : 160 + (k - 80));
                const float* src = W_r + (size_t)wrow * 64;
                float acc = 0.f;
                for (int m = 0; m < 64; ++m)
                    acc = fmaf(src[m], Wc2[m * 10 + c], acc);
                A[arow * 16 + c] = acc;
            } else if (g < 3606) {
                const int c = g - 3596;
                float acc = 0.f;
                for (int m = 0; m < 64; ++m)
                    acc = fmaf(b_r[m], Wc2[m * 10 + c], acc);
                A[224 * 16 + c] = acc;
            } else {
                const int c = g - 3606;
                float acc = b_s[c];
                for (int j = 0; j < 64; ++j)
                    acc = fmaf(b_o[j], W_s[j * 10 + c], acc);
                A[225 * 16 + c] = acc;
            }
        }
    } else {
        // ---- count_rank role: atomic's return value IS the rank ----
        const int bt = (blockIdx.x - NB_PRE) * 256 + t;
        if (bt * 4 >= N_EDGES) return;
        const int4 r4 = reinterpret_cast<const int4*>(receivers)[bt];
        int4 k4;
        k4.x = atomicAdd(count + r4.x, 1);
        k4.y = atomicAdd(count + r4.y, 1);
        k4.z = atomicAdd(count + r4.z, 1);
        k4.w = atomicAdd(count + r4.w, 1);
        reinterpret_cast<int4*>(rank)[bt] = k4;
    }
}

// ---------------------------------------------------------------------------
// Fused K2: blocks [0,NB_ALLOC) segment-alloc; blocks [NB_ALLOC,..) node_u.
// alloc needs count (K1); node_u needs A (K1). Disjoint outputs.
// ---------------------------------------------------------------------------
__global__ __launch_bounds__(256) void fused_mid_kernel(
    const float* __restrict__ O, const float* __restrict__ X,
    const float* __restrict__ A,
    const int* __restrict__ count, unsigned int* __restrict__ cursor,
    int* __restrict__ off,
    float* __restrict__ us, float* __restrict__ u01)
{
    __shared__ float2 lA[226 * 5];  // used by node_u role only
    const int t = threadIdx.x;

    if (blockIdx.x < NB_ALLOC) {
        // ---- alloc role: wave-aggregated prefix, 1 atomic per wave.
        // Prefix is node-ordered within each 64-node wave chunk -> any
        // 16-aligned node group owns a contiguous wsort range (node_score).
        const int n = blockIdx.x * 256 + t;
        const int lane = t & 63;
        const int c = (n < N_NODES) ? count[n] : 0;

        int pre = c;
#pragma unroll
        for (int d = 1; d < 64; d <<= 1) {
            const int v = __shfl_up(pre, d);
            if (lane >= d) pre += v;
        }
        const int total = __shfl(pre, 63);
        int base = 0;
        if (lane == 63) base = (int)atomicAdd(cursor, (unsigned int)total);
        base = __shfl(base, 63);

        if (n < N_NODES) off[n] = base + pre - c;  // exclusive prefix
    } else {
        // ---- node_u role: thread = (node, class-PAIR), A staged in LDS ----
        for (int i = t; i < 226 * 5; i += 256) {
            const int row = i / 5, cp = i - row * 5;
            lA[i] = *reinterpret_cast<const float2*>(A + (size_t)row * 16 + 2 * cp);
        }
        __syncthreads();

        const int tid = (blockIdx.x - NB_ALLOC) * 256 + t;
        if (tid >= N_NODES * 5) return;
        const int n = tid / 5;
        const int cp = tid - n * 5;

        float vs0 = 0.f, vs1 = 0.f, v00 = 0.f, v01 = 0.f, v10 = 0.f, v11 = 0.f;

        const float4* Ov = reinterpret_cast<const float4*>(O + (size_t)n * 64);
#pragma unroll
        for (int kc = 0; kc < 16; ++kc) {
            const float4 o4 = Ov[kc];
#pragma unroll
            for (int j = 0; j < 4; ++j) {
                const float ov = (j == 0) ? o4.x : (j == 1) ? o4.y : (j == 2) ? o4.z : o4.w;
                const int k = kc * 4 + j;
                const float2 aO = lA[k * 5 + cp];
                const float2 aS = lA[(80 + k) * 5 + cp];
                const float2 aD = lA[(160 + k) * 5 + cp];
                v00 = fmaf(ov, aO.x, v00); v01 = fmaf(ov, aO.y, v01);
                vs0 = fmaf(ov, aS.x, vs0); vs1 = fmaf(ov, aS.y, vs1);
                v10 = fmaf(ov, aD.x, v10); v11 = fmaf(ov, aD.y, v11);
            }
        }
        const float4* Xv = reinterpret_cast<const float4*>(X + (size_t)n * 16);
#pragma unroll
        for (int kc = 0; kc < 4; ++kc) {
            const float4 x4 = Xv[kc];
#pragma unroll
            for (int j = 0; j < 4; ++j) {
                const float xv = (j == 0) ? x4.x : (j == 1) ? x4.y : (j == 2) ? x4.z : x4.w;
                const int k = 64 + kc * 4 + j;
                const float2 aX = lA[k * 5 + cp];
                v00 = fmaf(xv, aX.x, v00); v01 = fmaf(xv, aX.y, v01);
            }
        }

        const float2 c0 = lA[224 * 5 + cp];
        const float2 c1 = lA[225 * 5 + cp];
        *reinterpret_cast<float2*>(us + (size_t)n * 12 + 2 * cp) = make_float2(vs0, vs1);
        *reinterpret_cast<float2*>(u01 + (size_t)n * 20 + 2 * cp) =
            make_float2(v00 + c1.x, v01 + c1.y);
        *reinterpret_cast<float2*>(u01 + (size_t)n * 20 + 10 + 2 * cp) =
            make_float2(v10 + c0.x, v11 + c0.y);
    }
}

// ---------------------------------------------------------------------------
// Per-edge w_e = u_s[s_e] + R_a[e]@A_R -> bf16-packed, written directly to
// receiver-sorted slot pos = off[r] + rank[e]. No atomic. Plain stores.
// ---------------------------------------------------------------------------
__global__ __launch_bounds__(256) void edge_w_kernel(
    const float* __restrict__ R_a,
    const int* __restrict__ senders, const int* __restrict__ receivers,
    const int* __restrict__ rank, const int* __restrict__ off,
    const float* __restrict__ us, const float* __restrict__ A,
    unsigned int* __restrict__ wsort)   // [E][5] dwords, receiver-sorted
{
    const int e = blockIdx.x * blockDim.x + threadIdx.x;
    if (e >= N_EDGES) return;
    const int s = senders[e];
    const int r = receivers[e];
    const int pos = off[r] + rank[e];   // plain loads — no atomic

    // u_s[s]: 48 B gather from L2-resident 2.4 MB table
    const float4* U = reinterpret_cast<const float4*>(us + (size_t)s * 12);
    const float4 ua = U[0];
    const float4 ub = U[1];
    const float4 uc = U[2];
    float a[10] = {ua.x, ua.y, ua.z, ua.w, ub.x, ub.y, ub.z, ub.w, uc.x, uc.y};

    // R_a[e] @ A_R (A rows 144..159) — R_a streamed coalesced
    const float4* Rv = reinterpret_cast<const float4*>(R_a + (size_t)e * 16);
#pragma unroll
    for (int kc = 0; kc < 4; ++kc) {
        const float4 b4 = Rv[kc];
        const float* A0 = A + (size_t)(144 + kc * 4) * 16;
#pragma unroll
        for (int c = 0; c < 10; ++c) a[c] = fmaf(b4.x, A0[c], a[c]);
#pragma unroll
        for (int c = 0; c < 10; ++c) a[c] = fmaf(b4.y, A0[16 + c], a[c]);
#pragma unroll
        for (int c = 0; c < 10; ++c) a[c] = fmaf(b4.z, A0[32 + c], a[c]);
#pragma unroll
        for (int c = 0; c < 10; ++c) a[c] = fmaf(b4.w, A0[48 + c], a[c]);
    }

    unsigned int* wp = wsort + (size_t)pos * 5;
    wp[0] = f32_to_bf16_rne(a[0]) | (f32_to_bf16_rne(a[1]) << 16);
    wp[1] = f32_to_bf16_rne(a[2]) | (f32_to_bf16_rne(a[3]) << 16);
    wp[2] = f32_to_bf16_rne(a[4]) | (f32_to_bf16_rne(a[5]) << 16);
    wp[3] = f32_to_bf16_rne(a[6]) | (f32_to_bf16_rne(a[7]) << 16);
    wp[4] = f32_to_bf16_rne(a[8]) | (f32_to_bf16_rne(a[9]) << 16);
}

// ---------------------------------------------------------------------------
// Node scores (r15): block = 16 aligned nodes = one CONTIGUOUS wsort range.
// Stream range into LDS coalesced (512-record chunks), reduce from LDS.
// ---------------------------------------------------------------------------
#define CH_REC 512   // records per LDS chunk (2560 dwords = 10,240 B)

__global__ __launch_bounds__(256) void node_score_kernel(
    const float* __restrict__ u01,
    const int* __restrict__ off, const int* __restrict__ count,
    const unsigned int* __restrict__ w,   // [E][5] dwords, receiver-sorted
    float* __restrict__ out)
{
    __shared__ unsigned int lw[CH_REC * 5];
    const int t = threadIdx.x;
    const int n0 = blockIdx.x * 16;        // 16 | 64 -> block range contiguous
    const int g = t >> 4;                  // group 0..15 -> node n0+g
    const int lane = t & 15;
    const int n = n0 + g;                  // N_NODES % 16 == 0

    const int beg16 = off[n0];
    const int end16 = off[n0 + 15] + count[n0 + 15];

    const int beg = off[n];
    const int cnt = count[n];
    const int dge = cnt;

    const int cc = (lane < 10) ? lane : 0;
    const int half = cc >> 1;
    const int sh = (cc & 1) * 16;

    float sc = u01[(size_t)n * 20 + cc] + (float)dge * u01[(size_t)n * 20 + 10 + cc];

    for (int c0 = beg16; c0 < end16; c0 += CH_REC) {
        const int nrec = min(CH_REC, end16 - c0);
        const int ndw = nrec * 5;
        __syncthreads();
        for (int i = t; i < ndw; i += 256)
            lw[i] = w[(size_t)c0 * 5 + i];
        __syncthreads();

        const int j0 = max(beg, c0);
        const int j1 = min(beg + cnt, c0 + nrec);
        for (int j = j0; j < j1; ++j) {
            const unsigned int v = lw[(j - c0) * 5 + half];
            sc += __uint_as_float((v >> sh) << 16);
        }
    }

    // softmax over the 10 active lanes of this 16-lane group
    float m = (lane < 10) ? sc : -3.0e38f;
#pragma unroll
    for (int d = 1; d < 16; d <<= 1) m = fmaxf(m, __shfl_xor(m, d, 16));
    const float ex = (lane < 10) ? __expf(sc - m) : 0.f;
    float sum = ex;
#pragma unroll
    for (int d = 1; d < 16; d <<= 1) sum += __shfl_xor(sum, d, 16);
    if (lane < 10) out[(size_t)n * 10 + lane] = ex / sum;
}

extern "C" void kernel_launch(void* const* d_in, const int* in_sizes, int n_in,
                              void* d_out, int out_size, void* d_ws, size_t ws_size,
                              hipStream_t stream)
{
    const float* O    = (const float*)d_in[0];
    const float* X    = (const float*)d_in[1];
    const float* R_a  = (const float*)d_in[2];
    const int* senders   = (const int*)d_in[3];
    const int* receivers = (const int*)d_in[4];
    const float* W_r  = (const float*)d_in[5];
    const float* b_r  = (const float*)d_in[6];
    const float* W_o  = (const float*)d_in[7];
    const float* b_o  = (const float*)d_in[8];
    const float* W_s  = (const float*)d_in[9];
    const float* b_s  = (const float*)d_in[10];
    float* out = (float*)d_out;
    char* ws = (char*)d_ws;

    float* A      = (float*)(ws + WS_A);
    int* count    = (int*)(ws + WS_COUNT);
    unsigned int* cursor = (unsigned int*)(ws + WS_CURSOR);
    int* off      = (int*)(ws + WS_OFF);
    int* rank     = (int*)(ws + WS_RANK);
    float* us     = (float*)(ws + WS_US);
    float* u01    = (float*)(ws + WS_U01);
    unsigned int* wsort = (unsigned int*)(ws + WS_WSORT);

    // zero count histogram + cursor (adjacent) in one memset
    hipMemsetAsync(count, 0, (size_t)(200000 + 4 + 384), stream);

    fused_prep_kernel<<<NB_PRE + NB_CR, 256, 0, stream>>>(
        W_r, b_r, W_o, b_o, W_s, b_s, receivers, A, count, rank);

    fused_mid_kernel<<<NB_ALLOC + NB_NU, 256, 0, stream>>>(
        O, X, A, count, cursor, off, us, u01);

    edge_w_kernel<<<(N_EDGES + 255) / 256, 256, 0, stream>>>(
        R_a, senders, receivers, rank, off, us, A, wsort);

    node_score_kernel<<<N_NODES / 16, 256, 0, stream>>>(
        u01, off, count, wsort, out);
}